// Round 6
// baseline (98.928 us; speedup 1.0000x reference)
//
#include <hip/hip_runtime.h>

// SkipGram negative-sampling loss on MI355X — round 6.
// R5 structure + sched_barrier(0) fences to FORCE the depth-8 pipeline
// (R5's VGPR=56 proved the scheduler sank the prefetch loads; 8 slots
// need 64 VGPRs minimum, so the manual pipeline never reached the .s).

#define VOCAB  100000
#define EMB    128
#define B_TOT  16384
#define W_POS  10
#define K_NEG  64
#define N_LAB  (W_POS + K_NEG)   // 74
#define NCHUNK 19                // ceil(74/4)
#define DEPTH  8                 // row-load pipeline depth

__device__ __forceinline__ float logsig(float x) {
    // log_sigmoid(x) = min(x,0) - log1p(exp(-|x|)); hw exp/log only.
    const float e = __expf(-fabsf(x));
    return fminf(x, 0.0f) - 0.69314718056f * __log2f(1.0f + e);
}

__global__ __launch_bounds__(256, 4) void skipgram_kernel(
    const int*   __restrict__ input,       // [B]
    const int*   __restrict__ pos_labels,  // [B, W_POS]
    const int*   __restrict__ neg_labels,  // [B, K_NEG]
    const float* __restrict__ input_emb,   // [VOCAB, EMB]
    const float* __restrict__ output_emb,  // [VOCAB, EMB]
    float*       __restrict__ out)         // [1]
{
    const int lane = threadIdx.x & 63;
    const int gl   = lane & 15;   // lane within 16-lane group
    const int grp  = lane >> 4;   // which label of each 4-label chunk
    const int wave = (int)((blockIdx.x * blockDim.x + threadIdx.x) >> 6);
    const int b    = wave;        // one element per wave, grid sized exactly

    const int* pl = pos_labels + b * W_POS;
    const int* nl = neg_labels + b * K_NEG;

    // ---- all index loads up front (independent, all in flight) ----
    int idx[NCHUNK];
    #pragma unroll
    for (int t = 0; t < NCHUNK; ++t) {
        const int j = 4 * t + grp;
        idx[t] = (j < W_POS) ? pl[j] : ((j < N_LAB) ? nl[j - W_POS] : 0);
    }

    // ---- center row ----
    const int c = input[b];
    const float4* crow = (const float4*)(input_emb + (size_t)c * EMB);
    const float4 c0 = crow[gl * 2], c1 = crow[gl * 2 + 1];

    // ---- depth-8 pipelined row gathers: prologue issues 16 loads ----
    float4 A[DEPTH][2];
    #pragma unroll
    for (int t = 0; t < DEPTH; ++t) {
        const float4* rp = (const float4*)(output_emb + (size_t)idx[t] * EMB);
        A[t][0] = rp[gl * 2];
        A[t][1] = rp[gl * 2 + 1];
    }
    // Hard fence: no prologue load may sink past this point.
    __builtin_amdgcn_sched_barrier(0);

    float acc = 0.0f;

    #pragma unroll
    for (int t = 0; t < NCHUNK; ++t) {
        const float4 a0 = A[t % DEPTH][0];
        const float4 a1 = A[t % DEPTH][1];

        // Refill this slot with chunk t+DEPTH, issued BEFORE this chunk's
        // compute; fence keeps it there.
        if (t + DEPTH < NCHUNK) {
            const float4* rp =
                (const float4*)(output_emb + (size_t)idx[t + DEPTH] * EMB);
            A[t % DEPTH][0] = rp[gl * 2];
            A[t % DEPTH][1] = rp[gl * 2 + 1];
        }
        __builtin_amdgcn_sched_barrier(0);

        float p = a0.x * c0.x + a0.y * c0.y + a0.z * c0.z + a0.w * c0.w
                + a1.x * c1.x + a1.y * c1.y + a1.z * c1.z + a1.w * c1.w;

        p += __shfl_xor(p, 1);
        p += __shfl_xor(p, 2);
        p += __shfl_xor(p, 4);
        p += __shfl_xor(p, 8);

        const int j = 4 * t + grp;
        if (gl == 0 && j < N_LAB) acc += logsig(p);
    }

    // ---- wave reduce (group leaders) then block reduce -> 1 atomic ----
    acc += __shfl_xor(acc, 16);
    acc += __shfl_xor(acc, 32);

    __shared__ float part[4];
    if (lane == 0) part[threadIdx.x >> 6] = acc;
    __syncthreads();
    if (threadIdx.x == 0) {
        const float s = part[0] + part[1] + part[2] + part[3];
        atomicAdd(out, -s);
    }
}

extern "C" void kernel_launch(void* const* d_in, const int* in_sizes, int n_in,
                              void* d_out, int out_size, void* d_ws, size_t ws_size,
                              hipStream_t stream) {
    const int*   input      = (const int*)  d_in[0];
    const int*   pos_labels = (const int*)  d_in[1];
    const int*   neg_labels = (const int*)  d_in[2];
    const float* input_emb  = (const float*)d_in[3];
    const float* output_emb = (const float*)d_in[4];
    float*       out        = (float*)      d_out;

    // d_out is poisoned (0xAA) and not re-zeroed between replays.
    hipMemsetAsync(out, 0, sizeof(float), stream);

    // 4096 blocks x 256 threads = 16384 waves -> exactly 1 element per wave.
    dim3 grid(4096), block(256);
    hipLaunchKernelGGL(skipgram_kernel, grid, block, 0, stream,
                       input, pos_labels, neg_labels, input_emb, output_emb, out);
}

// Round 7
// 94.552 us; speedup vs baseline: 1.0463x; 1.0463x over previous
//
#include <hip/hip_runtime.h>

// SkipGram negative-sampling loss on MI355X — round 7.
// R5 body (depth-8 pipeline request, no sched fences) + longer-lived
// blocks: 2048 blocks, each wave loops over 2 batch elements.
// R1 (2048 blocks) had 63% occupancy vs R4-R6 (4096 blocks) 35-44% —
// block lifetime, not per-wave ILP, is the remaining MLP lever.

#define VOCAB  100000
#define EMB    128
#define B_TOT  16384
#define W_POS  10
#define K_NEG  64
#define N_LAB  (W_POS + K_NEG)   // 74
#define NCHUNK 19                // ceil(74/4)
#define DEPTH  8                 // row-load pipeline depth (request)

__device__ __forceinline__ float logsig(float x) {
    // log_sigmoid(x) = min(x,0) - log1p(exp(-|x|)); hw exp/log only.
    const float e = __expf(-fabsf(x));
    return fminf(x, 0.0f) - 0.69314718056f * __log2f(1.0f + e);
}

__global__ __launch_bounds__(256, 4) void skipgram_kernel(
    const int*   __restrict__ input,       // [B]
    const int*   __restrict__ pos_labels,  // [B, W_POS]
    const int*   __restrict__ neg_labels,  // [B, K_NEG]
    const float* __restrict__ input_emb,   // [VOCAB, EMB]
    const float* __restrict__ output_emb,  // [VOCAB, EMB]
    float*       __restrict__ out)         // [1]
{
    const int lane = threadIdx.x & 63;
    const int gl   = lane & 15;   // lane within 16-lane group
    const int grp  = lane >> 4;   // which label of each 4-label chunk
    const int wave = (int)((blockIdx.x * blockDim.x + threadIdx.x) >> 6);

    float acc = 0.0f;

    #pragma unroll 1
    for (int b = wave * 2; b < wave * 2 + 2; ++b) {
        const int* pl = pos_labels + b * W_POS;
        const int* nl = neg_labels + b * K_NEG;

        // ---- all index loads up front (independent, all in flight) ----
        int idx[NCHUNK];
        #pragma unroll
        for (int t = 0; t < NCHUNK; ++t) {
            const int j = 4 * t + grp;
            idx[t] = (j < W_POS) ? pl[j] : ((j < N_LAB) ? nl[j - W_POS] : 0);
        }

        // ---- center row ----
        const int c = input[b];
        const float4* crow = (const float4*)(input_emb + (size_t)c * EMB);
        const float4 c0 = crow[gl * 2], c1 = crow[gl * 2 + 1];

        // ---- pipelined row gathers ----
        float4 A[DEPTH][2];
        #pragma unroll
        for (int t = 0; t < DEPTH; ++t) {
            const float4* rp = (const float4*)(output_emb + (size_t)idx[t] * EMB);
            A[t][0] = rp[gl * 2];
            A[t][1] = rp[gl * 2 + 1];
        }

        #pragma unroll
        for (int t = 0; t < NCHUNK; ++t) {
            const float4 a0 = A[t % DEPTH][0];
            const float4 a1 = A[t % DEPTH][1];

            // refill this slot with chunk t+DEPTH (static after unroll)
            if (t + DEPTH < NCHUNK) {
                const float4* rp =
                    (const float4*)(output_emb + (size_t)idx[t + DEPTH] * EMB);
                A[t % DEPTH][0] = rp[gl * 2];
                A[t % DEPTH][1] = rp[gl * 2 + 1];
            }

            float p = a0.x * c0.x + a0.y * c0.y + a0.z * c0.z + a0.w * c0.w
                    + a1.x * c1.x + a1.y * c1.y + a1.z * c1.z + a1.w * c1.w;

            p += __shfl_xor(p, 1);
            p += __shfl_xor(p, 2);
            p += __shfl_xor(p, 4);
            p += __shfl_xor(p, 8);

            const int j = 4 * t + grp;
            if (gl == 0 && j < N_LAB) acc += logsig(p);
        }
    }

    // ---- wave reduce (group leaders) then block reduce -> 1 atomic ----
    acc += __shfl_xor(acc, 16);
    acc += __shfl_xor(acc, 32);

    __shared__ float part[4];
    if (lane == 0) part[threadIdx.x >> 6] = acc;
    __syncthreads();
    if (threadIdx.x == 0) {
        const float s = part[0] + part[1] + part[2] + part[3];
        atomicAdd(out, -s);
    }
}

extern "C" void kernel_launch(void* const* d_in, const int* in_sizes, int n_in,
                              void* d_out, int out_size, void* d_ws, size_t ws_size,
                              hipStream_t stream) {
    const int*   input      = (const int*)  d_in[0];
    const int*   pos_labels = (const int*)  d_in[1];
    const int*   neg_labels = (const int*)  d_in[2];
    const float* input_emb  = (const float*)d_in[3];
    const float* output_emb = (const float*)d_in[4];
    float*       out        = (float*)      d_out;

    // d_out is poisoned (0xAA) and not re-zeroed between replays.
    hipMemsetAsync(out, 0, sizeof(float), stream);

    // 2048 blocks x 256 threads = 8192 waves x 2 elements each.
    dim3 grid(2048), block(256);
    hipLaunchKernelGGL(skipgram_kernel, grid, block, 0, stream,
                       input, pos_labels, neg_labels, input_emb, output_emb, out);
}